// Round 13
// baseline (229.131 us; speedup 1.0000x reference)
//
#include <hip/hip_runtime.h>
#include <stdint.h>
#include <stddef.h>

#define NB  64
#define ND  256
#define NLC 1024
#define NLQ 128
#define INVKEEP (1.0f/0.9f)

// ---- workspace layout (float offsets); total 14,835,712 floats = 56.6 MiB ----
#define OFF_SQP   0u            // NB*4*128   sq partials (4 chunks)
#define OFF_U     32768u        // NB*NLC     u(i) = exp(rmax_i)*rowsum_i
#define OFF_V     98304u        // NB*NLQ     v(j) = exp(-cmax_j)/colsum_j
#define OFF_COLP  106496u       // NB*8*128*2 col partials (m,s)
#define OFF_SBT   237568u       // NB*NLQ*NLC bf16 S_^T
#define OFF_QT    4431872u      // NB*NLQ*ND  bf16 Q'^T (wm*Q+wc, [j][d])
#define OFF_SBF   8544256u      // NB*NLC*NLQ bf16 S_
#define OFF_M     12738560u     // NB*ND*NLQ  bf16 M
#define OFF_QB    13787136u     // NB*ND*NLQ  bf16 Q

typedef float f32x4  __attribute__((ext_vector_type(4)));
typedef short bf16x8 __attribute__((ext_vector_type(8)));

__device__ __forceinline__ uint32_t f2bf(float x) {
  const uint32_t u = __float_as_uint(x);
  return (u + 0x7fffu + ((u >> 16) & 1u)) >> 16;
}
__device__ __forceinline__ uint32_t cvtpk(float lo, float hi) {
  uint32_t r;
  asm("v_cvt_pk_bf16_f32 %0, %1, %2" : "=v"(r) : "v"(lo), "v"(hi));
  return r;
}

// ================= threefry2x32, key=(0,42); bits = o0^o1 (verified r2) =====
__device__ __forceinline__ void tf_round(uint32_t& a, uint32_t& b, const int r) {
  a += b;
  b = (b << r) | (b >> (32 - r));
  b ^= a;
}
__device__ __forceinline__ uint32_t threefry_xor(uint32_t x0, uint32_t x1) {
  const uint32_t ks0 = 0u, ks1 = 42u, ks2 = 0x1BD11BDAu ^ 0u ^ 42u;
  x0 += ks0; x1 += ks1;
  tf_round(x0,x1,13); tf_round(x0,x1,15); tf_round(x0,x1,26); tf_round(x0,x1,6);
  x0 += ks1; x1 += ks2 + 1u;
  tf_round(x0,x1,17); tf_round(x0,x1,29); tf_round(x0,x1,16); tf_round(x0,x1,24);
  x0 += ks2; x1 += ks0 + 2u;
  tf_round(x0,x1,13); tf_round(x0,x1,15); tf_round(x0,x1,26); tf_round(x0,x1,6);
  x0 += ks0; x1 += ks1 + 3u;
  tf_round(x0,x1,17); tf_round(x0,x1,29); tf_round(x0,x1,16); tf_round(x0,x1,24);
  x0 += ks1; x1 += ks2 + 4u;
  tf_round(x0,x1,13); tf_round(x0,x1,15); tf_round(x0,x1,26); tf_round(x0,x1,6);
  x0 += ks2; x1 += ks0 + 5u;
  return x0 ^ x1;
}

// ===== prep: Q -> QB bf16 [d][j], Q'^T bf16 [j][d], sq partials ==============
__global__ __launch_bounds__(256) void k_prep(const float* __restrict__ Q,
                                              const float* __restrict__ W,
                                              float* __restrict__ ws) {
  __shared__ __align__(16) float Qs[64][129];
  __shared__ float wqS[64], wmS[64], wcS[64];
  __shared__ float red[8][128];
  const int n = blockIdx.x;
  const int b = n >> 2, c = n & 3;
  const int d0 = c * 64;
  const int t = threadIdx.x;
  if (t < 64) {
    wqS[t] = W[(size_t)b*768 + d0 + t];
    wcS[t] = W[(size_t)b*768 + 256 + d0 + t];
    wmS[t] = W[(size_t)b*768 + 512 + d0 + t];
  }
  __syncthreads();
  const float* Qb = Q + (size_t)b*ND*NLQ;
  ushort* QBg = (ushort*)(ws + OFF_QB) + (size_t)b*ND*NLQ;
  const int j4 = t & 31, y = t >> 5;
  float sq4[4] = {0.0f, 0.0f, 0.0f, 0.0f};
  #pragma unroll
  for (int p = 0; p < 8; ++p) {
    const int dk = p*8 + y;
    const float4 qv = *(const float4*)&Qb[(size_t)(d0+dk)*NLQ + j4*4];
    *(float4*)&Qs[dk][j4*4] = qv;
    uint2 pk;
    pk.x = cvtpk(qv.x, qv.y);
    pk.y = cvtpk(qv.z, qv.w);
    *(uint2*)&QBg[(size_t)(d0+dk)*NLQ + j4*4] = pk;
    const float wq = wqS[dk];
    sq4[0] = fmaf(wq, qv.x, sq4[0]);
    sq4[1] = fmaf(wq, qv.y, sq4[1]);
    sq4[2] = fmaf(wq, qv.z, sq4[2]);
    sq4[3] = fmaf(wq, qv.w, sq4[3]);
  }
  #pragma unroll
  for (int e = 0; e < 4; ++e) red[y][j4*4 + e] = sq4[e];
  __syncthreads();
  const int j = t >> 1, dh = (t & 1) * 32;
  uint32_t pk16[16];
  #pragma unroll
  for (int kk = 0; kk < 32; kk += 2) {
    const float q0 = fmaf(wmS[dh+kk],   Qs[dh+kk][j],   wcS[dh+kk]);
    const float q1 = fmaf(wmS[dh+kk+1], Qs[dh+kk+1][j], wcS[dh+kk+1]);
    pk16[kk >> 1] = cvtpk(q0, q1);
  }
  ushort* QTg = (ushort*)(ws + OFF_QT) + (size_t)b*NLQ*ND + (size_t)j*ND + d0 + dh;
  *(uint4*)&QTg[0]  = *(uint4*)&pk16[0];
  *(uint4*)&QTg[8]  = *(uint4*)&pk16[4];
  *(uint4*)&QTg[16] = *(uint4*)&pk16[8];
  *(uint4*)&QTg[24] = *(uint4*)&pk16[12];
  if (t < 128) {
    float s = 0.0f;
    #pragma unroll
    for (int yy = 0; yy < 8; ++yy) s += red[yy][t];
    ws[OFF_SQP + ((size_t)b*4 + c)*128 + t] = s;
  }
}

// ===== S (MFMA): fused row softmax; writes S_ bf16, S_^T bf16, u, col partials
__global__ __launch_bounds__(256) void k_s(const float* __restrict__ C,
                                           float* __restrict__ ws) {
  __shared__ __align__(16) uint8_t smem[37376];
  float  (*Cs)[129] = (float(*)[129])smem;                // [d 32][i 128] fp32
  ushort (*Qt)[40]  = (ushort(*)[40])(smem + 16512);      // [j 128][d 32] bf16
  ushort (*T)[128]  = (ushort(*)[128])smem;               // phase2: 32KB
  float*  sqS       = (float*)(smem + 32768);             // 128 f (safe zone)
  float  (*colm)[128] = (float(*)[128])(smem + 33280);
  float  (*cols)[128] = (float(*)[128])(smem + 35328);

  const int n  = blockIdx.x;
  const int rr = n & 7, qq = n >> 3;
  const int it = qq & 7;                 // member: i-tile
  const int b  = (qq >> 3) * 8 + rr;     // group: batch (same XCD)
  const int i0 = it * 128;
  const int t  = threadIdx.x;
  if (t < 128) {
    const float* sp = ws + OFF_SQP + (size_t)b*4*128 + t;
    sqS[t] = sp[0] + sp[128] + sp[256] + sp[384];
  }

  const float*  Cb  = C + (size_t)b*ND*NLC;
  const ushort* QTg = (const ushort*)(ws + OFF_QT) + (size_t)b*NLQ*ND;
  const int l  = t & 63, w = t >> 6;
  const int lm = l & 15, lg = l >> 4;

  f32x4 acc[2][8];
  #pragma unroll
  for (int mg = 0; mg < 2; ++mg)
    #pragma unroll
    for (int nf = 0; nf < 8; ++nf) acc[mg][nf] = (f32x4)0.0f;

  for (int d0 = 0; d0 < ND; d0 += 32) {
    __syncthreads();
    #pragma unroll
    for (int p = 0; p < 4; ++p) {        // stage C tile fp32 (coalesced)
      const int f  = p*256 + t;
      const int dk = f >> 5, x4 = f & 31;
      *(float4*)&Cs[dk][x4*4] = *(const float4*)&Cb[(size_t)(d0+dk)*NLC + i0 + x4*4];
    }
    #pragma unroll
    for (int p = 0; p < 2; ++p) {        // stage Q'^T tile: pure uint4 copies
      const int f  = p*256 + t;
      const int jr = f >> 2, k8 = (f & 3)*8;
      *(uint4*)&Qt[jr][k8] = *(const uint4*)&QTg[(size_t)jr*ND + d0 + k8];
    }
    __syncthreads();
    bf16x8 bq[8];
    #pragma unroll
    for (int nf = 0; nf < 8; ++nf)       // B-frags: one b128 each
      bq[nf] = *(const bf16x8*)&Qt[nf*16 + lm][lg*8];
    #pragma unroll
    for (int mg = 0; mg < 2; ++mg) {
      const int i = w*32 + mg*16 + lm;
      union { uint32_t u[4]; bf16x8 v; } ca;
      #pragma unroll
      for (int kk = 0; kk < 4; ++kk)
        ca.u[kk] = cvtpk(Cs[lg*8 + kk*2][i], Cs[lg*8 + kk*2 + 1][i]);
      #pragma unroll
      for (int nf = 0; nf < 8; ++nf)
        acc[mg][nf] = __builtin_amdgcn_mfma_f32_16x16x32_bf16(ca.v, bq[nf], acc[mg][nf], 0, 0, 0);
    }
  }

  float sqv[8];
  #pragma unroll
  for (int nf = 0; nf < 8; ++nf) sqv[nf] = sqS[nf*16 + lm];
  __syncthreads();   // staging dead; smem becomes T/colm/cols

  // --- row softmax -> T (swizzled), u write ---
  #pragma unroll
  for (int mg = 0; mg < 2; ++mg) {
    #pragma unroll
    for (int r = 0; r < 4; ++r) {
      const int row = w*32 + mg*16 + lg*4 + r;
      float sv[8], e[8];
      #pragma unroll
      for (int nf = 0; nf < 8; ++nf) sv[nf] = acc[mg][nf][r] + sqv[nf];
      float mx = sv[0];
      #pragma unroll
      for (int nf = 1; nf < 8; ++nf) mx = fmaxf(mx, sv[nf]);
      mx = fmaxf(mx, __shfl_xor(mx, 1));
      mx = fmaxf(mx, __shfl_xor(mx, 2));
      mx = fmaxf(mx, __shfl_xor(mx, 4));
      mx = fmaxf(mx, __shfl_xor(mx, 8));
      float sm = 0.0f;
      #pragma unroll
      for (int nf = 0; nf < 8; ++nf) { e[nf] = __expf(sv[nf] - mx); sm += e[nf]; }
      sm += __shfl_xor(sm, 1); sm += __shfl_xor(sm, 2);
      sm += __shfl_xor(sm, 4); sm += __shfl_xor(sm, 8);
      const float ir = 1.0f / sm;
      const int po = ((row & 7) ^ ((row >> 3) & 7)) << 3;
      #pragma unroll
      for (int nf = 0; nf < 8; ++nf)
        T[row][(nf*16 + lm) ^ po] = (ushort)f2bf(e[nf] * ir);
      if (lm == 0) ws[OFF_U + (size_t)b*NLC + i0 + row] = __expf(mx) * sm;
    }
  }

  // --- column partial stats ---
  float cmx[8];
  #pragma unroll
  for (int nf = 0; nf < 8; ++nf) {
    float m2 = -3.0e38f;
    #pragma unroll
    for (int mg = 0; mg < 2; ++mg)
      #pragma unroll
      for (int r = 0; r < 4; ++r)
        m2 = fmaxf(m2, acc[mg][nf][r] + sqv[nf]);
    m2 = fmaxf(m2, __shfl_xor(m2, 16));
    m2 = fmaxf(m2, __shfl_xor(m2, 32));
    cmx[nf] = m2;
  }
  if (lg == 0) {
    #pragma unroll
    for (int nf = 0; nf < 8; ++nf) colm[w][nf*16 + lm] = cmx[nf];
  }
  __syncthreads();
  #pragma unroll
  for (int nf = 0; nf < 8; ++nf) {
    const int j = nf*16 + lm;
    const float cmb = fmaxf(fmaxf(colm[0][j], colm[1][j]),
                            fmaxf(colm[2][j], colm[3][j]));
    float cs = 0.0f;
    #pragma unroll
    for (int mg = 0; mg < 2; ++mg)
      #pragma unroll
      for (int r = 0; r < 4; ++r)
        cs += __expf(acc[mg][nf][r] + sqv[nf] - cmb);
    cs += __shfl_xor(cs, 16);
    cs += __shfl_xor(cs, 32);
    if (lg == 0) cols[w][j] = cs;
  }
  __syncthreads();

  // --- outputs: SBF rows, SBT transposed, colp partials ---
  ushort* Sb16 = (ushort*)(ws + OFF_SBF) + ((size_t)b*NLC + (size_t)i0)*NLQ;
  #pragma unroll
  for (int p = 0; p < 8; ++p) {
    const int f = p*256 + t;
    const int i = f >> 4, jo = f & 15;
    const int po = ((i & 7) ^ ((i >> 3) & 7)) << 3;
    *(uint4*)&Sb16[(size_t)i*NLQ + jo*8] = *(const uint4*)&T[i][(jo*8) ^ po];
  }
  ushort* SBTg = (ushort*)(ws + OFF_SBT) + (size_t)b*NLQ*NLC + i0;
  #pragma unroll
  for (int p = 0; p < 8; ++p) {
    const int f = p*256 + t;
    const int j = f >> 4, io = f & 15;
    uint32_t wd4[4];
    #pragma unroll
    for (int h = 0; h < 4; ++h) {
      const uint32_t v0 = T[io*8 + h*2    ][j ^ (((h*2    ) ^ (io & 7)) << 3)];
      const uint32_t v1 = T[io*8 + h*2 + 1][j ^ (((h*2 + 1) ^ (io & 7)) << 3)];
      wd4[h] = v0 | (v1 << 16);
    }
    *(uint4*)&SBTg[(size_t)j*NLC + io*8] = *(uint4*)wd4;
  }
  if (t < 128) {
    const float cm = fmaxf(fmaxf(colm[0][t], colm[1][t]),
                           fmaxf(colm[2][t], colm[3][t]));
    const float s  = cols[0][t] + cols[1][t] + cols[2][t] + cols[3][t];
    float2* cp = (float2*)(ws + OFF_COLP) + ((size_t)b*8 + it)*128 + t;
    *cp = make_float2(cm, s);
  }
}

// ===== merge col partials -> v(j) = exp(-cmax)/colsum ========================
__global__ __launch_bounds__(128) void k_cred(float* __restrict__ ws) {
  const int b = blockIdx.x, j = threadIdx.x;
  const float2* cp = (const float2*)(ws + OFF_COLP) + (size_t)b*8*128 + j;
  float m = -3.0e38f, s = 0.0f;
  #pragma unroll
  for (int it = 0; it < 8; ++it) {
    const float2 p = cp[(size_t)it*128];
    const float nm = fmaxf(m, p.x);
    s = s * __expf(m - nm) + p.y * __expf(p.x - nm);
    m = nm;
  }
  ws[OFF_V + (size_t)b*NLQ + j] = __expf(-m) / s;
}

// ===== M (MFMA): M[d,j] = v(j) * sum_k (C[d,k]*u(k)) * S_[k,j], K-step 64 ===
__global__ __launch_bounds__(256) void k_m(const float* __restrict__ C,
                                           float* __restrict__ ws) {
  __shared__ ushort Cp[32][72];
  __shared__ ushort Ts[128][72];
  __shared__ float u_l[1024];
  __shared__ float v_l[128];
  const int n  = blockIdx.x;
  const int rr = n & 7, qq = n >> 3;
  const int dq = qq & 7;                // member: d-tile (32 rows)
  const int b  = (qq >> 3) * 8 + rr;    // group: batch (same XCD)
  const int t  = threadIdx.x;
  const int l  = t & 63, w = t >> 6;
  const int wd = w & 1, wj = w >> 1;
  const int lm = l & 15, lg = l >> 4;
  for (int kk = t; kk < 1024; kk += 256) u_l[kk] = ws[OFF_U + (size_t)b*NLC + kk];
  if (t < 128) v_l[t] = ws[OFF_V + (size_t)b*NLQ + t];

  f32x4 acc[4];
  #pragma unroll
  for (int nf = 0; nf < 4; ++nf) acc[nf] = (f32x4)0.0f;

  const float*  Cb   = C + (size_t)b*ND*NLC + (size_t)dq*32*NLC;
  const ushort* SBTg = (const ushort*)(ws + OFF_SBT) + (size_t)b*NLQ*NLC;

  for (int kt = 0; kt < 16; ++kt) {
    const int k0 = kt*64;
    __syncthreads();
    {                                    // stage C' = C*u (32 d x 64 k)
      const int dl = t >> 3, kq = t & 7;
      const float4 c0 = *(const float4*)&Cb[(size_t)dl*NLC + k0 + kq*8];
      const float4 c1 = *(const float4*)&Cb[(size_t)dl*NLC + k0 + kq*8 + 4];
      const int kb = k0 + kq*8;
      uint4 pk;
      pk.x = cvtpk(c0.x * u_l[kb+0], c0.y * u_l[kb+1]);
      pk.y = cvtpk(c0.z * u_l[kb+2], c0.w * u_l[kb+3]);
      pk.z = cvtpk(c1.x * u_l[kb+4], c1.y * u_l[kb+5]);
      pk.w = cvtpk(c1.z * u_l[kb+6], c1.w * u_l[kb+7]);
      *(uint4*)&Cp[dl][kq*8] = pk;
    }
    #pragma unroll
    for (int p = 0; p < 4; ++p) {        // stage S_^T tile (128 j x 64 k)
      const int f = p*256 + t;
      const int jr = f >> 3, k8 = (f & 7)*8;
      *(uint4*)&Ts[jr][k8] = *(const uint4*)&SBTg[(size_t)jr*NLC + k0 + k8];
    }
    __syncthreads();
    #pragma unroll
    for (int ks = 0; ks < 2; ++ks) {
      union { uint32_t u[4]; bf16x8 v; } ca;
      *(uint4*)ca.u = *(const uint4*)&Cp[wd*16 + lm][ks*32 + lg*8];
      #pragma unroll
      for (int nf = 0; nf < 4; ++nf) {
        union { uint32_t u[4]; bf16x8 v; } cb;
        *(uint4*)cb.u = *(const uint4*)&Ts[wj*64 + nf*16 + lm][ks*32 + lg*8];
        acc[nf] = __builtin_amdgcn_mfma_f32_16x16x32_bf16(ca.v, cb.v, acc[nf], 0, 0, 0);
      }
    }
  }
  ushort* Mp = (ushort*)(ws + OFF_M) + (size_t)b*ND*NLQ + (size_t)dq*32*NLQ;
  #pragma unroll
  for (int nf = 0; nf < 4; ++nf) {
    const int j = wj*64 + nf*16 + lm;
    const float vj = v_l[j];
    #pragma unroll
    for (int r = 0; r < 4; ++r) {
      const int d = wd*16 + lg*4 + r;
      Mp[(size_t)d*NLQ + j] = (ushort)f2bf(acc[nf][r] * vj);
    }
  }
}

// ==== final (MFMA, swapped operands): A-op = S_, B-op = Q/M =================
// D[m=i][n=d]: thread holds 4 CONSECUTIVE i at fixed d -> direct full-line
// stores, NO LDS output transpose. Q/M frags live in registers (global load);
// LDS = St only (32 KB) -> 5 blocks/CU.
__global__ __launch_bounds__(256, 5) void k_final(const float* __restrict__ C,
                                                  float* __restrict__ ws,
                                                  float* __restrict__ out) {
  __shared__ __align__(16) ushort St[128][128];   // [i][j] bf16, swizzled

  const int n  = blockIdx.x;
  const int r8 = n & 7, q = n >> 3;       // q in 0..1023
  const int m  = q & 15;                  // member: d0 block (16 rows)
  const int g  = (q >> 4) * 8 + r8;       // group 0..511 = (i0, b), one XCD
  const int b  = g & 63;
  const int i0 = (g >> 6) * 128;
  const int d0 = m * 16;
  const int t  = threadIdx.x;

  const ushort* Sp = (const ushort*)(ws + OFF_SBF) + ((size_t)b*NLC + i0)*NLQ;
  #pragma unroll
  for (int p = 0; p < 8; ++p) {           // S_ bf16: swizzled uint4 copies
    const int f  = p*256 + t;
    const int jo = f & 15;
    const int il = f >> 4;
    *(uint4*)&St[il][(jo*8) ^ ((il & 7) << 3)] =
        *(const uint4*)&Sp[(size_t)il*NLQ + jo*8];
  }

  const int w  = t >> 6;
  const int l  = t & 63;
  const int lm = l & 15;
  const int lg = l >> 4;
  const int sw = (lm & 7) << 3;

  // B-operand (Q, M) fragments: straight from global into registers.
  // frag layout: lane n=lm -> row d0+lm, k = ks*32 + lg*8 (8 contiguous j).
  const ushort* Qp = (const ushort*)(ws + OFF_QB) + ((size_t)b*ND + d0 + lm)*NLQ;
  const ushort* Mp = (const ushort*)(ws + OFF_M)  + ((size_t)b*ND + d0 + lm)*NLQ;
  bf16x8 qf[4], mf[4];
  #pragma unroll
  for (int ks = 0; ks < 4; ++ks) {
    qf[ks] = *(const bf16x8*)&Qp[ks*32 + lg*8];
    mf[ks] = *(const bf16x8*)&Mp[ks*32 + lg*8];
  }
  __syncthreads();

  f32x4 accA[2], accB[2];
  #pragma unroll
  for (int f = 0; f < 2; ++f) { accA[f] = (f32x4)0.0f; accB[f] = (f32x4)0.0f; }

  #pragma unroll
  for (int ks = 0; ks < 4; ++ks) {
    const int koff = (ks*32 + lg*8) ^ sw;
    #pragma unroll
    for (int f = 0; f < 2; ++f) {
      const bf16x8 sf = *(const bf16x8*)&St[(w*2 + f)*16 + lm][koff];
      accA[f] = __builtin_amdgcn_mfma_f32_16x16x32_bf16(sf, qf[ks], accA[f], 0, 0, 0);
      accB[f] = __builtin_amdgcn_mfma_f32_16x16x32_bf16(sf, mf[ks], accB[f], 0, 0, 0);
    }
  }

  // epilogue: thread owns d = d0+lm, i = i0 + w*32 + f*16 + lg*4 (+r).
  // Wave covers one aligned 128B line per d-row, completed by the f=0/f=1
  // store pair (adjacent instructions -> no partial-line RMW).
  const int d  = d0 + lm;
  const int ib = i0 + w*32 + lg*4;
  const float* Crow = C + ((size_t)b*ND + d)*NLC;
  const float4 c0 = *(const float4*)&Crow[ib];
  const float4 c1 = *(const float4*)&Crow[ib + 16];
  const float cv0[4] = {c0.x, c0.y, c0.z, c0.w};
  const float cv1[4] = {c1.x, c1.y, c1.z, c1.w};
  #pragma unroll 1                        // small body: fits L1I
  for (int s = 0; s < 4; ++s) {
    const uint32_t nb0 = ((((uint32_t)b << 10) + (uint32_t)(s*ND + d)) << 10)
                         + (uint32_t)ib;
    float o0[4], o1[4];
    #pragma unroll
    for (int e = 0; e < 4; ++e) {
      const uint32_t bits0 = threefry_xor(0u, nb0 + (uint32_t)e);
      const uint32_t bits1 = threefry_xor(0u, nb0 + 16u + (uint32_t)e);
      float va, vb;
      if (s == 0)      { va = cv0[e];             vb = cv1[e]; }
      else if (s == 1) { va = accA[0][e];         vb = accA[1][e]; }
      else if (s == 2) { va = cv0[e]*accA[0][e];  vb = cv1[e]*accA[1][e]; }
      else             { va = cv0[e]*accB[0][e];  vb = cv1[e]*accB[1][e]; }
      // u < 0.9f  <=>  bits>>9 < 7549747  <=>  bits < 7549747*512
      o0[e] = (bits0 < 3865470464u) ? va * INVKEEP : 0.0f;
      o1[e] = (bits1 < 3865470464u) ? vb * INVKEEP : 0.0f;
    }
    *(float4*)&out[nb0]       = make_float4(o0[0], o0[1], o0[2], o0[3]);
    *(float4*)&out[nb0 + 16]  = make_float4(o1[0], o1[1], o1[2], o1[3]);
  }
}

extern "C" void kernel_launch(void* const* d_in, const int* in_sizes, int n_in,
                              void* d_out, int out_size, void* d_ws, size_t ws_size,
                              hipStream_t stream) {
  (void)in_sizes; (void)n_in; (void)out_size; (void)ws_size;
  const float* C = (const float*)d_in[0];
  const float* Q = (const float*)d_in[1];
  const float* W = (const float*)d_in[2];
  float* out = (float*)d_out;
  float* ws  = (float*)d_ws;

  hipLaunchKernelGGL(k_prep,  dim3(256),  dim3(256), 0, stream, Q, W, ws);
  hipLaunchKernelGGL(k_s,     dim3(512),  dim3(256), 0, stream, C, ws);
  hipLaunchKernelGGL(k_cred,  dim3(NB),   dim3(128), 0, stream, ws);
  hipLaunchKernelGGL(k_m,     dim3(512),  dim3(256), 0, stream, C, ws);
  hipLaunchKernelGGL(k_final, dim3(8192), dim3(256), 0, stream, C, ws, out);
}

// Round 14
// 190.955 us; speedup vs baseline: 1.1999x; 1.1999x over previous
//
#include <hip/hip_runtime.h>
#include <stdint.h>
#include <stddef.h>

#define NB  64
#define ND  256
#define NLC 1024
#define NLQ 128
#define INVKEEP (1.0f/0.9f)

// ---- workspace layout (float offsets); total 14,835,712 floats = 56.6 MiB ----
#define OFF_SQP   0u            // NB*4*128   sq partials (4 chunks)
#define OFF_U     32768u        // NB*NLC     u(i) = exp(rmax_i)*rowsum_i
#define OFF_V     98304u        // NB*NLQ     v(j) = exp(-cmax_j)/colsum_j
#define OFF_COLP  106496u       // NB*8*128*2 col partials (m,s)
#define OFF_SBT   237568u       // NB*NLQ*NLC bf16 S_^T
#define OFF_QT    4431872u      // NB*NLQ*ND  bf16 Q'^T (wm*Q+wc, [j][d])
#define OFF_SBF   8544256u      // NB*NLC*NLQ bf16 S_
#define OFF_M     12738560u     // NB*ND*NLQ  bf16 M
#define OFF_QB    13787136u     // NB*ND*NLQ  bf16 Q

typedef float f32x4  __attribute__((ext_vector_type(4)));
typedef short bf16x8 __attribute__((ext_vector_type(8)));

__device__ __forceinline__ uint32_t f2bf(float x) {
  const uint32_t u = __float_as_uint(x);
  return (u + 0x7fffu + ((u >> 16) & 1u)) >> 16;
}
__device__ __forceinline__ uint32_t cvtpk(float lo, float hi) {
  uint32_t r;
  asm("v_cvt_pk_bf16_f32 %0, %1, %2" : "=v"(r) : "v"(lo), "v"(hi));
  return r;
}

// ================= threefry2x32, key=(0,42); bits = o0^o1 (verified r2) =====
__device__ __forceinline__ void tf_round(uint32_t& a, uint32_t& b, const int r) {
  a += b;
  b = (b << r) | (b >> (32 - r));
  b ^= a;
}
__device__ __forceinline__ uint32_t threefry_xor(uint32_t x0, uint32_t x1) {
  const uint32_t ks0 = 0u, ks1 = 42u, ks2 = 0x1BD11BDAu ^ 0u ^ 42u;
  x0 += ks0; x1 += ks1;
  tf_round(x0,x1,13); tf_round(x0,x1,15); tf_round(x0,x1,26); tf_round(x0,x1,6);
  x0 += ks1; x1 += ks2 + 1u;
  tf_round(x0,x1,17); tf_round(x0,x1,29); tf_round(x0,x1,16); tf_round(x0,x1,24);
  x0 += ks2; x1 += ks0 + 2u;
  tf_round(x0,x1,13); tf_round(x0,x1,15); tf_round(x0,x1,26); tf_round(x0,x1,6);
  x0 += ks0; x1 += ks1 + 3u;
  tf_round(x0,x1,17); tf_round(x0,x1,29); tf_round(x0,x1,16); tf_round(x0,x1,24);
  x0 += ks1; x1 += ks2 + 4u;
  tf_round(x0,x1,13); tf_round(x0,x1,15); tf_round(x0,x1,26); tf_round(x0,x1,6);
  x0 += ks2; x1 += ks0 + 5u;
  return x0 ^ x1;
}

// ===== prep: Q -> QB bf16 [d][j], Q'^T bf16 [j][d], sq partials ==============
__global__ __launch_bounds__(256) void k_prep(const float* __restrict__ Q,
                                              const float* __restrict__ W,
                                              float* __restrict__ ws) {
  __shared__ __align__(16) float Qs[64][129];
  __shared__ float wqS[64], wmS[64], wcS[64];
  __shared__ float red[8][128];
  const int n = blockIdx.x;
  const int b = n >> 2, c = n & 3;
  const int d0 = c * 64;
  const int t = threadIdx.x;
  if (t < 64) {
    wqS[t] = W[(size_t)b*768 + d0 + t];
    wcS[t] = W[(size_t)b*768 + 256 + d0 + t];
    wmS[t] = W[(size_t)b*768 + 512 + d0 + t];
  }
  __syncthreads();
  const float* Qb = Q + (size_t)b*ND*NLQ;
  ushort* QBg = (ushort*)(ws + OFF_QB) + (size_t)b*ND*NLQ;
  const int j4 = t & 31, y = t >> 5;
  float sq4[4] = {0.0f, 0.0f, 0.0f, 0.0f};
  #pragma unroll
  for (int p = 0; p < 8; ++p) {
    const int dk = p*8 + y;
    const float4 qv = *(const float4*)&Qb[(size_t)(d0+dk)*NLQ + j4*4];
    *(float4*)&Qs[dk][j4*4] = qv;
    uint2 pk;
    pk.x = cvtpk(qv.x, qv.y);
    pk.y = cvtpk(qv.z, qv.w);
    *(uint2*)&QBg[(size_t)(d0+dk)*NLQ + j4*4] = pk;
    const float wq = wqS[dk];
    sq4[0] = fmaf(wq, qv.x, sq4[0]);
    sq4[1] = fmaf(wq, qv.y, sq4[1]);
    sq4[2] = fmaf(wq, qv.z, sq4[2]);
    sq4[3] = fmaf(wq, qv.w, sq4[3]);
  }
  #pragma unroll
  for (int e = 0; e < 4; ++e) red[y][j4*4 + e] = sq4[e];
  __syncthreads();
  const int j = t >> 1, dh = (t & 1) * 32;
  uint32_t pk16[16];
  #pragma unroll
  for (int kk = 0; kk < 32; kk += 2) {
    const float q0 = fmaf(wmS[dh+kk],   Qs[dh+kk][j],   wcS[dh+kk]);
    const float q1 = fmaf(wmS[dh+kk+1], Qs[dh+kk+1][j], wcS[dh+kk+1]);
    pk16[kk >> 1] = cvtpk(q0, q1);
  }
  ushort* QTg = (ushort*)(ws + OFF_QT) + (size_t)b*NLQ*ND + (size_t)j*ND + d0 + dh;
  *(uint4*)&QTg[0]  = *(uint4*)&pk16[0];
  *(uint4*)&QTg[8]  = *(uint4*)&pk16[4];
  *(uint4*)&QTg[16] = *(uint4*)&pk16[8];
  *(uint4*)&QTg[24] = *(uint4*)&pk16[12];
  if (t < 128) {
    float s = 0.0f;
    #pragma unroll
    for (int yy = 0; yy < 8; ++yy) s += red[yy][t];
    ws[OFF_SQP + ((size_t)b*4 + c)*128 + t] = s;
  }
}

// ===== S (MFMA): fused row softmax; writes S_ bf16, S_^T bf16, u, col partials
__global__ __launch_bounds__(256) void k_s(const float* __restrict__ C,
                                           float* __restrict__ ws) {
  __shared__ __align__(16) uint8_t smem[37376];
  float  (*Cs)[129] = (float(*)[129])smem;                // [d 32][i 128] fp32
  ushort (*Qt)[40]  = (ushort(*)[40])(smem + 16512);      // [j 128][d 32] bf16
  ushort (*T)[128]  = (ushort(*)[128])smem;               // phase2: 32KB
  float*  sqS       = (float*)(smem + 32768);             // 128 f (safe zone)
  float  (*colm)[128] = (float(*)[128])(smem + 33280);
  float  (*cols)[128] = (float(*)[128])(smem + 35328);

  const int n  = blockIdx.x;
  const int rr = n & 7, qq = n >> 3;
  const int it = qq & 7;                 // member: i-tile
  const int b  = (qq >> 3) * 8 + rr;     // group: batch (same XCD)
  const int i0 = it * 128;
  const int t  = threadIdx.x;
  if (t < 128) {
    const float* sp = ws + OFF_SQP + (size_t)b*4*128 + t;
    sqS[t] = sp[0] + sp[128] + sp[256] + sp[384];
  }

  const float*  Cb  = C + (size_t)b*ND*NLC;
  const ushort* QTg = (const ushort*)(ws + OFF_QT) + (size_t)b*NLQ*ND;
  const int l  = t & 63, w = t >> 6;
  const int lm = l & 15, lg = l >> 4;

  f32x4 acc[2][8];
  #pragma unroll
  for (int mg = 0; mg < 2; ++mg)
    #pragma unroll
    for (int nf = 0; nf < 8; ++nf) acc[mg][nf] = (f32x4)0.0f;

  for (int d0 = 0; d0 < ND; d0 += 32) {
    __syncthreads();
    #pragma unroll
    for (int p = 0; p < 4; ++p) {        // stage C tile fp32 (coalesced)
      const int f  = p*256 + t;
      const int dk = f >> 5, x4 = f & 31;
      *(float4*)&Cs[dk][x4*4] = *(const float4*)&Cb[(size_t)(d0+dk)*NLC + i0 + x4*4];
    }
    #pragma unroll
    for (int p = 0; p < 2; ++p) {        // stage Q'^T tile: pure uint4 copies
      const int f  = p*256 + t;
      const int jr = f >> 2, k8 = (f & 3)*8;
      *(uint4*)&Qt[jr][k8] = *(const uint4*)&QTg[(size_t)jr*ND + d0 + k8];
    }
    __syncthreads();
    bf16x8 bq[8];
    #pragma unroll
    for (int nf = 0; nf < 8; ++nf)       // B-frags: one b128 each
      bq[nf] = *(const bf16x8*)&Qt[nf*16 + lm][lg*8];
    #pragma unroll
    for (int mg = 0; mg < 2; ++mg) {
      const int i = w*32 + mg*16 + lm;
      union { uint32_t u[4]; bf16x8 v; } ca;
      #pragma unroll
      for (int kk = 0; kk < 4; ++kk)
        ca.u[kk] = cvtpk(Cs[lg*8 + kk*2][i], Cs[lg*8 + kk*2 + 1][i]);
      #pragma unroll
      for (int nf = 0; nf < 8; ++nf)
        acc[mg][nf] = __builtin_amdgcn_mfma_f32_16x16x32_bf16(ca.v, bq[nf], acc[mg][nf], 0, 0, 0);
    }
  }

  float sqv[8];
  #pragma unroll
  for (int nf = 0; nf < 8; ++nf) sqv[nf] = sqS[nf*16 + lm];
  __syncthreads();   // staging dead; smem becomes T/colm/cols

  // --- row softmax -> T (swizzled), u write ---
  #pragma unroll
  for (int mg = 0; mg < 2; ++mg) {
    #pragma unroll
    for (int r = 0; r < 4; ++r) {
      const int row = w*32 + mg*16 + lg*4 + r;
      float sv[8], e[8];
      #pragma unroll
      for (int nf = 0; nf < 8; ++nf) sv[nf] = acc[mg][nf][r] + sqv[nf];
      float mx = sv[0];
      #pragma unroll
      for (int nf = 1; nf < 8; ++nf) mx = fmaxf(mx, sv[nf]);
      mx = fmaxf(mx, __shfl_xor(mx, 1));
      mx = fmaxf(mx, __shfl_xor(mx, 2));
      mx = fmaxf(mx, __shfl_xor(mx, 4));
      mx = fmaxf(mx, __shfl_xor(mx, 8));
      float sm = 0.0f;
      #pragma unroll
      for (int nf = 0; nf < 8; ++nf) { e[nf] = __expf(sv[nf] - mx); sm += e[nf]; }
      sm += __shfl_xor(sm, 1); sm += __shfl_xor(sm, 2);
      sm += __shfl_xor(sm, 4); sm += __shfl_xor(sm, 8);
      const float ir = 1.0f / sm;
      const int po = ((row & 7) ^ ((row >> 3) & 7)) << 3;
      #pragma unroll
      for (int nf = 0; nf < 8; ++nf)
        T[row][(nf*16 + lm) ^ po] = (ushort)f2bf(e[nf] * ir);
      if (lm == 0) ws[OFF_U + (size_t)b*NLC + i0 + row] = __expf(mx) * sm;
    }
  }

  // --- column partial stats ---
  float cmx[8];
  #pragma unroll
  for (int nf = 0; nf < 8; ++nf) {
    float m2 = -3.0e38f;
    #pragma unroll
    for (int mg = 0; mg < 2; ++mg)
      #pragma unroll
      for (int r = 0; r < 4; ++r)
        m2 = fmaxf(m2, acc[mg][nf][r] + sqv[nf]);
    m2 = fmaxf(m2, __shfl_xor(m2, 16));
    m2 = fmaxf(m2, __shfl_xor(m2, 32));
    cmx[nf] = m2;
  }
  if (lg == 0) {
    #pragma unroll
    for (int nf = 0; nf < 8; ++nf) colm[w][nf*16 + lm] = cmx[nf];
  }
  __syncthreads();
  #pragma unroll
  for (int nf = 0; nf < 8; ++nf) {
    const int j = nf*16 + lm;
    const float cmb = fmaxf(fmaxf(colm[0][j], colm[1][j]),
                            fmaxf(colm[2][j], colm[3][j]));
    float cs = 0.0f;
    #pragma unroll
    for (int mg = 0; mg < 2; ++mg)
      #pragma unroll
      for (int r = 0; r < 4; ++r)
        cs += __expf(acc[mg][nf][r] + sqv[nf] - cmb);
    cs += __shfl_xor(cs, 16);
    cs += __shfl_xor(cs, 32);
    if (lg == 0) cols[w][j] = cs;
  }
  __syncthreads();

  // --- outputs: SBF rows, SBT transposed, colp partials ---
  ushort* Sb16 = (ushort*)(ws + OFF_SBF) + ((size_t)b*NLC + (size_t)i0)*NLQ;
  #pragma unroll
  for (int p = 0; p < 8; ++p) {
    const int f = p*256 + t;
    const int i = f >> 4, jo = f & 15;
    const int po = ((i & 7) ^ ((i >> 3) & 7)) << 3;
    *(uint4*)&Sb16[(size_t)i*NLQ + jo*8] = *(const uint4*)&T[i][(jo*8) ^ po];
  }
  ushort* SBTg = (ushort*)(ws + OFF_SBT) + (size_t)b*NLQ*NLC + i0;
  #pragma unroll
  for (int p = 0; p < 8; ++p) {
    const int f = p*256 + t;
    const int j = f >> 4, io = f & 15;
    uint32_t wd4[4];
    #pragma unroll
    for (int h = 0; h < 4; ++h) {
      const uint32_t v0 = T[io*8 + h*2    ][j ^ (((h*2    ) ^ (io & 7)) << 3)];
      const uint32_t v1 = T[io*8 + h*2 + 1][j ^ (((h*2 + 1) ^ (io & 7)) << 3)];
      wd4[h] = v0 | (v1 << 16);
    }
    *(uint4*)&SBTg[(size_t)j*NLC + io*8] = *(uint4*)wd4;
  }
  if (t < 128) {
    const float cm = fmaxf(fmaxf(colm[0][t], colm[1][t]),
                           fmaxf(colm[2][t], colm[3][t]));
    const float s  = cols[0][t] + cols[1][t] + cols[2][t] + cols[3][t];
    float2* cp = (float2*)(ws + OFF_COLP) + ((size_t)b*8 + it)*128 + t;
    *cp = make_float2(cm, s);
  }
}

// ===== merge col partials -> v(j) = exp(-cmax)/colsum ========================
__global__ __launch_bounds__(128) void k_cred(float* __restrict__ ws) {
  const int b = blockIdx.x, j = threadIdx.x;
  const float2* cp = (const float2*)(ws + OFF_COLP) + (size_t)b*8*128 + j;
  float m = -3.0e38f, s = 0.0f;
  #pragma unroll
  for (int it = 0; it < 8; ++it) {
    const float2 p = cp[(size_t)it*128];
    const float nm = fmaxf(m, p.x);
    s = s * __expf(m - nm) + p.y * __expf(p.x - nm);
    m = nm;
  }
  ws[OFF_V + (size_t)b*NLQ + j] = __expf(-m) / s;
}

// ===== M (MFMA): M[d,j] = v(j) * sum_k (C[d,k]*u(k)) * S_[k,j], K-step 64 ===
__global__ __launch_bounds__(256) void k_m(const float* __restrict__ C,
                                           float* __restrict__ ws) {
  __shared__ ushort Cp[32][72];
  __shared__ ushort Ts[128][72];
  __shared__ float u_l[1024];
  __shared__ float v_l[128];
  const int n  = blockIdx.x;
  const int rr = n & 7, qq = n >> 3;
  const int dq = qq & 7;                // member: d-tile (32 rows)
  const int b  = (qq >> 3) * 8 + rr;    // group: batch (same XCD)
  const int t  = threadIdx.x;
  const int l  = t & 63, w = t >> 6;
  const int wd = w & 1, wj = w >> 1;
  const int lm = l & 15, lg = l >> 4;
  for (int kk = t; kk < 1024; kk += 256) u_l[kk] = ws[OFF_U + (size_t)b*NLC + kk];
  if (t < 128) v_l[t] = ws[OFF_V + (size_t)b*NLQ + t];

  f32x4 acc[4];
  #pragma unroll
  for (int nf = 0; nf < 4; ++nf) acc[nf] = (f32x4)0.0f;

  const float*  Cb   = C + (size_t)b*ND*NLC + (size_t)dq*32*NLC;
  const ushort* SBTg = (const ushort*)(ws + OFF_SBT) + (size_t)b*NLQ*NLC;

  for (int kt = 0; kt < 16; ++kt) {
    const int k0 = kt*64;
    __syncthreads();
    {                                    // stage C' = C*u (32 d x 64 k)
      const int dl = t >> 3, kq = t & 7;
      const float4 c0 = *(const float4*)&Cb[(size_t)dl*NLC + k0 + kq*8];
      const float4 c1 = *(const float4*)&Cb[(size_t)dl*NLC + k0 + kq*8 + 4];
      const int kb = k0 + kq*8;
      uint4 pk;
      pk.x = cvtpk(c0.x * u_l[kb+0], c0.y * u_l[kb+1]);
      pk.y = cvtpk(c0.z * u_l[kb+2], c0.w * u_l[kb+3]);
      pk.z = cvtpk(c1.x * u_l[kb+4], c1.y * u_l[kb+5]);
      pk.w = cvtpk(c1.z * u_l[kb+6], c1.w * u_l[kb+7]);
      *(uint4*)&Cp[dl][kq*8] = pk;
    }
    #pragma unroll
    for (int p = 0; p < 4; ++p) {        // stage S_^T tile (128 j x 64 k)
      const int f = p*256 + t;
      const int jr = f >> 3, k8 = (f & 7)*8;
      *(uint4*)&Ts[jr][k8] = *(const uint4*)&SBTg[(size_t)jr*NLC + k0 + k8];
    }
    __syncthreads();
    #pragma unroll
    for (int ks = 0; ks < 2; ++ks) {
      union { uint32_t u[4]; bf16x8 v; } ca;
      *(uint4*)ca.u = *(const uint4*)&Cp[wd*16 + lm][ks*32 + lg*8];
      #pragma unroll
      for (int nf = 0; nf < 4; ++nf) {
        union { uint32_t u[4]; bf16x8 v; } cb;
        *(uint4*)cb.u = *(const uint4*)&Ts[wj*64 + nf*16 + lm][ks*32 + lg*8];
        acc[nf] = __builtin_amdgcn_mfma_f32_16x16x32_bf16(ca.v, cb.v, acc[nf], 0, 0, 0);
      }
    }
  }
  ushort* Mp = (ushort*)(ws + OFF_M) + (size_t)b*ND*NLQ + (size_t)dq*32*NLQ;
  #pragma unroll
  for (int nf = 0; nf < 4; ++nf) {
    const int j = wj*64 + nf*16 + lm;
    const float vj = v_l[j];
    #pragma unroll
    for (int r = 0; r < 4; ++r) {
      const int d = wd*16 + lg*4 + r;
      Mp[(size_t)d*NLQ + j] = (ushort)f2bf(acc[nf][r] * vj);
    }
  }
}

// ==== final (MFMA, swapped operands A=S_, B=Q/M from swizzled LDS) ==========
// D[m=i][n=d]: thread holds 4 consecutive i at fixed d -> direct full-line
// stores, NO At/Bt transpose. Qt/Mt in LDS (round-12 staging) so VGPR stays
// low; launch_bounds (256,4) = round-12's proven regalloc regime.
__global__ __launch_bounds__(256, 4) void k_final(const float* __restrict__ C,
                                                  float* __restrict__ ws,
                                                  float* __restrict__ out) {
  __shared__ __align__(16) ushort St[128][128];   // [i][j] bf16, swizzled 32KB
  __shared__ __align__(16) ushort Qt[16][128];    // [d][j] bf16, swizzled  4KB
  __shared__ __align__(16) ushort Mt[16][128];    // [d][j] bf16, swizzled  4KB

  const int n  = blockIdx.x;
  const int r8 = n & 7, q = n >> 3;       // q in 0..1023
  const int m  = q & 15;                  // member: d0 block (16 rows)
  const int g  = (q >> 4) * 8 + r8;       // group 0..511 = (i0, b), one XCD
  const int b  = g & 63;
  const int i0 = (g >> 6) * 128;
  const int d0 = m * 16;
  const int t  = threadIdx.x;

  const ushort* Sp = (const ushort*)(ws + OFF_SBF) + ((size_t)b*NLC + i0)*NLQ;
  #pragma unroll
  for (int p = 0; p < 8; ++p) {           // S_ bf16: swizzled uint4 copies
    const int f  = p*256 + t;
    const int jo = f & 15;
    const int il = f >> 4;
    *(uint4*)&St[il][(jo*8) ^ ((il & 7) << 3)] =
        *(const uint4*)&Sp[(size_t)il*NLQ + jo*8];
  }
  const ushort* Qp = (const ushort*)(ws + OFF_QB) + (size_t)b*ND*NLQ + (size_t)d0*NLQ;
  const ushort* Mp = (const ushort*)(ws + OFF_M)  + (size_t)b*ND*NLQ + (size_t)d0*NLQ;
  {                                       // Q/M bf16: swizzled uint4 copies
    const int jo = t & 15;
    const int dl = t >> 4;
    const int col = (jo*8) ^ ((dl & 7) << 3);
    *(uint4*)&Qt[dl][col] = *(const uint4*)&Qp[(size_t)dl*NLQ + jo*8];
    *(uint4*)&Mt[dl][col] = *(const uint4*)&Mp[(size_t)dl*NLQ + jo*8];
  }
  __syncthreads();

  const int w  = t >> 6;
  const int l  = t & 63;
  const int lm = l & 15;
  const int lg = l >> 4;
  const int sw = (lm & 7) << 3;

  f32x4 accA[2], accB[2];
  #pragma unroll
  for (int f = 0; f < 2; ++f) { accA[f] = (f32x4)0.0f; accB[f] = (f32x4)0.0f; }

  #pragma unroll
  for (int ks = 0; ks < 4; ++ks) {
    const int koff = (ks*32 + lg*8) ^ sw;
    const bf16x8 qfk = *(const bf16x8*)&Qt[lm][koff];  // B-frag: row d0+lm
    const bf16x8 mfk = *(const bf16x8*)&Mt[lm][koff];
    #pragma unroll
    for (int f = 0; f < 2; ++f) {
      const bf16x8 sf = *(const bf16x8*)&St[(w*2 + f)*16 + lm][koff];
      accA[f] = __builtin_amdgcn_mfma_f32_16x16x32_bf16(sf, qfk, accA[f], 0, 0, 0);
      accB[f] = __builtin_amdgcn_mfma_f32_16x16x32_bf16(sf, mfk, accB[f], 0, 0, 0);
    }
  }

  // epilogue: thread owns d = d0+lm, i = i0 + w*32 + f*16 + lg*4 (+r 0..3).
  // Per d-row the wave covers one aligned 128B line via the adjacent f=0/f=1
  // store pair (64B + 64B) -> no partial-line RMW window.
  const int d  = d0 + lm;
  const int ib = i0 + w*32 + lg*4;
  const float* Crow = C + ((size_t)b*ND + d)*NLC;
  const float4 c0 = *(const float4*)&Crow[ib];
  const float4 c1 = *(const float4*)&Crow[ib + 16];
  const float cv0[4] = {c0.x, c0.y, c0.z, c0.w};
  const float cv1[4] = {c1.x, c1.y, c1.z, c1.w};
  #pragma unroll 2                        // s compile-time per copy; body ~16
  for (int s = 0; s < 4; ++s) {           // threefry = round-12's working size
    const uint32_t nb0 = ((((uint32_t)b << 10) + (uint32_t)(s*ND + d)) << 10)
                         + (uint32_t)ib;
    float o0[4], o1[4];
    #pragma unroll
    for (int e = 0; e < 4; ++e) {
      const uint32_t bits0 = threefry_xor(0u, nb0 + (uint32_t)e);
      const uint32_t bits1 = threefry_xor(0u, nb0 + 16u + (uint32_t)e);
      float va, vb;
      if (s == 0)      { va = cv0[e];             vb = cv1[e]; }
      else if (s == 1) { va = accA[0][e];         vb = accA[1][e]; }
      else if (s == 2) { va = cv0[e]*accA[0][e];  vb = cv1[e]*accA[1][e]; }
      else             { va = cv0[e]*accB[0][e];  vb = cv1[e]*accB[1][e]; }
      // u < 0.9f  <=>  bits>>9 < 7549747  <=>  bits < 7549747*512
      o0[e] = (bits0 < 3865470464u) ? va * INVKEEP : 0.0f;
      o1[e] = (bits1 < 3865470464u) ? vb * INVKEEP : 0.0f;
    }
    *(float4*)&out[nb0]      = make_float4(o0[0], o0[1], o0[2], o0[3]);
    *(float4*)&out[nb0 + 16] = make_float4(o1[0], o1[1], o1[2], o1[3]);
  }
}

extern "C" void kernel_launch(void* const* d_in, const int* in_sizes, int n_in,
                              void* d_out, int out_size, void* d_ws, size_t ws_size,
                              hipStream_t stream) {
  (void)in_sizes; (void)n_in; (void)out_size; (void)ws_size;
  const float* C = (const float*)d_in[0];
  const float* Q = (const float*)d_in[1];
  const float* W = (const float*)d_in[2];
  float* out = (float*)d_out;
  float* ws  = (float*)d_ws;

  hipLaunchKernelGGL(k_prep,  dim3(256),  dim3(256), 0, stream, Q, W, ws);
  hipLaunchKernelGGL(k_s,     dim3(512),  dim3(256), 0, stream, C, ws);
  hipLaunchKernelGGL(k_cred,  dim3(NB),   dim3(128), 0, stream, ws);
  hipLaunchKernelGGL(k_m,     dim3(512),  dim3(256), 0, stream, C, ws);
  hipLaunchKernelGGL(k_final, dim3(8192), dim3(256), 0, stream, C, ws, out);
}

// Round 15
// 183.721 us; speedup vs baseline: 1.2472x; 1.0394x over previous
//
#include <hip/hip_runtime.h>
#include <stdint.h>
#include <stddef.h>

#define NB  64
#define ND  256
#define NLC 1024
#define NLQ 128
#define INVKEEP (1.0f/0.9f)

// ---- workspace layout (float offsets); total 14,835,712 floats = 56.6 MiB ----
#define OFF_SQP   0u            // NB*4*128   sq partials (4 chunks)
#define OFF_U     32768u        // NB*NLC     u(i) = exp(rmax_i)*rowsum_i
#define OFF_V     98304u        // NB*NLQ     v(j) = exp(-cmax_j)/colsum_j
#define OFF_COLP  106496u       // NB*8*128*2 col partials (m,s)
#define OFF_SBT   237568u       // NB*NLQ*NLC bf16 S_^T
#define OFF_QT    4431872u      // NB*NLQ*ND  bf16 Q'^T (wm*Q+wc, [j][d])
#define OFF_SBF   8544256u      // NB*NLC*NLQ bf16 S_
#define OFF_M     12738560u     // NB*ND*NLQ  bf16 M
#define OFF_QB    13787136u     // NB*ND*NLQ  bf16 Q

typedef float f32x4  __attribute__((ext_vector_type(4)));
typedef short bf16x8 __attribute__((ext_vector_type(8)));

__device__ __forceinline__ uint32_t f2bf(float x) {
  const uint32_t u = __float_as_uint(x);
  return (u + 0x7fffu + ((u >> 16) & 1u)) >> 16;
}
__device__ __forceinline__ uint32_t cvtpk(float lo, float hi) {
  uint32_t r;
  asm("v_cvt_pk_bf16_f32 %0, %1, %2" : "=v"(r) : "v"(lo), "v"(hi));
  return r;
}

// ================= threefry2x32, key=(0,42); bits = o0^o1 (verified r2) =====
// rotate via __builtin_rotateleft32 -> single v_alignbit_b32 (vs shl+shr+or).
__device__ __forceinline__ void tf_round(uint32_t& a, uint32_t& b, const int r) {
  a += b;
  b = __builtin_rotateleft32(b, (uint32_t)r) ^ a;
}
__device__ __forceinline__ uint32_t threefry_xor(uint32_t x0, uint32_t x1) {
  const uint32_t ks0 = 0u, ks1 = 42u, ks2 = 0x1BD11BDAu ^ 0u ^ 42u;
  x0 += ks0; x1 += ks1;
  tf_round(x0,x1,13); tf_round(x0,x1,15); tf_round(x0,x1,26); tf_round(x0,x1,6);
  x0 += ks1; x1 += ks2 + 1u;
  tf_round(x0,x1,17); tf_round(x0,x1,29); tf_round(x0,x1,16); tf_round(x0,x1,24);
  x0 += ks2; x1 += ks0 + 2u;
  tf_round(x0,x1,13); tf_round(x0,x1,15); tf_round(x0,x1,26); tf_round(x0,x1,6);
  x0 += ks0; x1 += ks1 + 3u;
  tf_round(x0,x1,17); tf_round(x0,x1,29); tf_round(x0,x1,16); tf_round(x0,x1,24);
  x0 += ks1; x1 += ks2 + 4u;
  tf_round(x0,x1,13); tf_round(x0,x1,15); tf_round(x0,x1,26); tf_round(x0,x1,6);
  x0 += ks2; x1 += ks0 + 5u;
  return x0 ^ x1;
}

// ===== prep: Q -> QB bf16 [d][j], Q'^T bf16 [j][d], sq partials ==============
__global__ __launch_bounds__(256) void k_prep(const float* __restrict__ Q,
                                              const float* __restrict__ W,
                                              float* __restrict__ ws) {
  __shared__ __align__(16) float Qs[64][129];
  __shared__ float wqS[64], wmS[64], wcS[64];
  __shared__ float red[8][128];
  const int n = blockIdx.x;
  const int b = n >> 2, c = n & 3;
  const int d0 = c * 64;
  const int t = threadIdx.x;
  if (t < 64) {
    wqS[t] = W[(size_t)b*768 + d0 + t];
    wcS[t] = W[(size_t)b*768 + 256 + d0 + t];
    wmS[t] = W[(size_t)b*768 + 512 + d0 + t];
  }
  __syncthreads();
  const float* Qb = Q + (size_t)b*ND*NLQ;
  ushort* QBg = (ushort*)(ws + OFF_QB) + (size_t)b*ND*NLQ;
  const int j4 = t & 31, y = t >> 5;
  float sq4[4] = {0.0f, 0.0f, 0.0f, 0.0f};
  #pragma unroll
  for (int p = 0; p < 8; ++p) {
    const int dk = p*8 + y;
    const float4 qv = *(const float4*)&Qb[(size_t)(d0+dk)*NLQ + j4*4];
    *(float4*)&Qs[dk][j4*4] = qv;
    uint2 pk;
    pk.x = cvtpk(qv.x, qv.y);
    pk.y = cvtpk(qv.z, qv.w);
    *(uint2*)&QBg[(size_t)(d0+dk)*NLQ + j4*4] = pk;
    const float wq = wqS[dk];
    sq4[0] = fmaf(wq, qv.x, sq4[0]);
    sq4[1] = fmaf(wq, qv.y, sq4[1]);
    sq4[2] = fmaf(wq, qv.z, sq4[2]);
    sq4[3] = fmaf(wq, qv.w, sq4[3]);
  }
  #pragma unroll
  for (int e = 0; e < 4; ++e) red[y][j4*4 + e] = sq4[e];
  __syncthreads();
  const int j = t >> 1, dh = (t & 1) * 32;
  uint32_t pk16[16];
  #pragma unroll
  for (int kk = 0; kk < 32; kk += 2) {
    const float q0 = fmaf(wmS[dh+kk],   Qs[dh+kk][j],   wcS[dh+kk]);
    const float q1 = fmaf(wmS[dh+kk+1], Qs[dh+kk+1][j], wcS[dh+kk+1]);
    pk16[kk >> 1] = cvtpk(q0, q1);
  }
  ushort* QTg = (ushort*)(ws + OFF_QT) + (size_t)b*NLQ*ND + (size_t)j*ND + d0 + dh;
  *(uint4*)&QTg[0]  = *(uint4*)&pk16[0];
  *(uint4*)&QTg[8]  = *(uint4*)&pk16[4];
  *(uint4*)&QTg[16] = *(uint4*)&pk16[8];
  *(uint4*)&QTg[24] = *(uint4*)&pk16[12];
  if (t < 128) {
    float s = 0.0f;
    #pragma unroll
    for (int yy = 0; yy < 8; ++yy) s += red[yy][t];
    ws[OFF_SQP + ((size_t)b*4 + c)*128 + t] = s;
  }
}

// ===== S (MFMA): fused row softmax; writes S_ bf16, S_^T bf16, u, col partials
__global__ __launch_bounds__(256) void k_s(const float* __restrict__ C,
                                           float* __restrict__ ws) {
  __shared__ __align__(16) uint8_t smem[37376];
  float  (*Cs)[129] = (float(*)[129])smem;                // [d 32][i 128] fp32
  ushort (*Qt)[40]  = (ushort(*)[40])(smem + 16512);      // [j 128][d 32] bf16
  ushort (*T)[128]  = (ushort(*)[128])smem;               // phase2: 32KB
  float*  sqS       = (float*)(smem + 32768);             // 128 f (safe zone)
  float  (*colm)[128] = (float(*)[128])(smem + 33280);
  float  (*cols)[128] = (float(*)[128])(smem + 35328);

  const int n  = blockIdx.x;
  const int rr = n & 7, qq = n >> 3;
  const int it = qq & 7;                 // member: i-tile
  const int b  = (qq >> 3) * 8 + rr;     // group: batch (same XCD)
  const int i0 = it * 128;
  const int t  = threadIdx.x;
  if (t < 128) {
    const float* sp = ws + OFF_SQP + (size_t)b*4*128 + t;
    sqS[t] = sp[0] + sp[128] + sp[256] + sp[384];
  }

  const float*  Cb  = C + (size_t)b*ND*NLC;
  const ushort* QTg = (const ushort*)(ws + OFF_QT) + (size_t)b*NLQ*ND;
  const int l  = t & 63, w = t >> 6;
  const int lm = l & 15, lg = l >> 4;

  f32x4 acc[2][8];
  #pragma unroll
  for (int mg = 0; mg < 2; ++mg)
    #pragma unroll
    for (int nf = 0; nf < 8; ++nf) acc[mg][nf] = (f32x4)0.0f;

  for (int d0 = 0; d0 < ND; d0 += 32) {
    __syncthreads();
    #pragma unroll
    for (int p = 0; p < 4; ++p) {        // stage C tile fp32 (coalesced)
      const int f  = p*256 + t;
      const int dk = f >> 5, x4 = f & 31;
      *(float4*)&Cs[dk][x4*4] = *(const float4*)&Cb[(size_t)(d0+dk)*NLC + i0 + x4*4];
    }
    #pragma unroll
    for (int p = 0; p < 2; ++p) {        // stage Q'^T tile: pure uint4 copies
      const int f  = p*256 + t;
      const int jr = f >> 2, k8 = (f & 3)*8;
      *(uint4*)&Qt[jr][k8] = *(const uint4*)&QTg[(size_t)jr*ND + d0 + k8];
    }
    __syncthreads();
    bf16x8 bq[8];
    #pragma unroll
    for (int nf = 0; nf < 8; ++nf)       // B-frags: one b128 each
      bq[nf] = *(const bf16x8*)&Qt[nf*16 + lm][lg*8];
    #pragma unroll
    for (int mg = 0; mg < 2; ++mg) {
      const int i = w*32 + mg*16 + lm;
      union { uint32_t u[4]; bf16x8 v; } ca;
      #pragma unroll
      for (int kk = 0; kk < 4; ++kk)
        ca.u[kk] = cvtpk(Cs[lg*8 + kk*2][i], Cs[lg*8 + kk*2 + 1][i]);
      #pragma unroll
      for (int nf = 0; nf < 8; ++nf)
        acc[mg][nf] = __builtin_amdgcn_mfma_f32_16x16x32_bf16(ca.v, bq[nf], acc[mg][nf], 0, 0, 0);
    }
  }

  float sqv[8];
  #pragma unroll
  for (int nf = 0; nf < 8; ++nf) sqv[nf] = sqS[nf*16 + lm];
  __syncthreads();   // staging dead; smem becomes T/colm/cols

  // --- row softmax -> T (swizzled), u write ---
  #pragma unroll
  for (int mg = 0; mg < 2; ++mg) {
    #pragma unroll
    for (int r = 0; r < 4; ++r) {
      const int row = w*32 + mg*16 + lg*4 + r;
      float sv[8], e[8];
      #pragma unroll
      for (int nf = 0; nf < 8; ++nf) sv[nf] = acc[mg][nf][r] + sqv[nf];
      float mx = sv[0];
      #pragma unroll
      for (int nf = 1; nf < 8; ++nf) mx = fmaxf(mx, sv[nf]);
      mx = fmaxf(mx, __shfl_xor(mx, 1));
      mx = fmaxf(mx, __shfl_xor(mx, 2));
      mx = fmaxf(mx, __shfl_xor(mx, 4));
      mx = fmaxf(mx, __shfl_xor(mx, 8));
      float sm = 0.0f;
      #pragma unroll
      for (int nf = 0; nf < 8; ++nf) { e[nf] = __expf(sv[nf] - mx); sm += e[nf]; }
      sm += __shfl_xor(sm, 1); sm += __shfl_xor(sm, 2);
      sm += __shfl_xor(sm, 4); sm += __shfl_xor(sm, 8);
      const float ir = 1.0f / sm;
      const int po = ((row & 7) ^ ((row >> 3) & 7)) << 3;
      #pragma unroll
      for (int nf = 0; nf < 8; ++nf)
        T[row][(nf*16 + lm) ^ po] = (ushort)f2bf(e[nf] * ir);
      if (lm == 0) ws[OFF_U + (size_t)b*NLC + i0 + row] = __expf(mx) * sm;
    }
  }

  // --- column partial stats ---
  float cmx[8];
  #pragma unroll
  for (int nf = 0; nf < 8; ++nf) {
    float m2 = -3.0e38f;
    #pragma unroll
    for (int mg = 0; mg < 2; ++mg)
      #pragma unroll
      for (int r = 0; r < 4; ++r)
        m2 = fmaxf(m2, acc[mg][nf][r] + sqv[nf]);
    m2 = fmaxf(m2, __shfl_xor(m2, 16));
    m2 = fmaxf(m2, __shfl_xor(m2, 32));
    cmx[nf] = m2;
  }
  if (lg == 0) {
    #pragma unroll
    for (int nf = 0; nf < 8; ++nf) colm[w][nf*16 + lm] = cmx[nf];
  }
  __syncthreads();
  #pragma unroll
  for (int nf = 0; nf < 8; ++nf) {
    const int j = nf*16 + lm;
    const float cmb = fmaxf(fmaxf(colm[0][j], colm[1][j]),
                            fmaxf(colm[2][j], colm[3][j]));
    float cs = 0.0f;
    #pragma unroll
    for (int mg = 0; mg < 2; ++mg)
      #pragma unroll
      for (int r = 0; r < 4; ++r)
        cs += __expf(acc[mg][nf][r] + sqv[nf] - cmb);
    cs += __shfl_xor(cs, 16);
    cs += __shfl_xor(cs, 32);
    if (lg == 0) cols[w][j] = cs;
  }
  __syncthreads();

  // --- outputs: SBF rows, SBT transposed, colp partials ---
  ushort* Sb16 = (ushort*)(ws + OFF_SBF) + ((size_t)b*NLC + (size_t)i0)*NLQ;
  #pragma unroll
  for (int p = 0; p < 8; ++p) {
    const int f = p*256 + t;
    const int i = f >> 4, jo = f & 15;
    const int po = ((i & 7) ^ ((i >> 3) & 7)) << 3;
    *(uint4*)&Sb16[(size_t)i*NLQ + jo*8] = *(const uint4*)&T[i][(jo*8) ^ po];
  }
  ushort* SBTg = (ushort*)(ws + OFF_SBT) + (size_t)b*NLQ*NLC + i0;
  #pragma unroll
  for (int p = 0; p < 8; ++p) {
    const int f = p*256 + t;
    const int j = f >> 4, io = f & 15;
    uint32_t wd4[4];
    #pragma unroll
    for (int h = 0; h < 4; ++h) {
      const uint32_t v0 = T[io*8 + h*2    ][j ^ (((h*2    ) ^ (io & 7)) << 3)];
      const uint32_t v1 = T[io*8 + h*2 + 1][j ^ (((h*2 + 1) ^ (io & 7)) << 3)];
      wd4[h] = v0 | (v1 << 16);
    }
    *(uint4*)&SBTg[(size_t)j*NLC + io*8] = *(uint4*)wd4;
  }
  if (t < 128) {
    const float cm = fmaxf(fmaxf(colm[0][t], colm[1][t]),
                           fmaxf(colm[2][t], colm[3][t]));
    const float s  = cols[0][t] + cols[1][t] + cols[2][t] + cols[3][t];
    float2* cp = (float2*)(ws + OFF_COLP) + ((size_t)b*8 + it)*128 + t;
    *cp = make_float2(cm, s);
  }
}

// ===== merge col partials -> v(j) = exp(-cmax)/colsum ========================
__global__ __launch_bounds__(128) void k_cred(float* __restrict__ ws) {
  const int b = blockIdx.x, j = threadIdx.x;
  const float2* cp = (const float2*)(ws + OFF_COLP) + (size_t)b*8*128 + j;
  float m = -3.0e38f, s = 0.0f;
  #pragma unroll
  for (int it = 0; it < 8; ++it) {
    const float2 p = cp[(size_t)it*128];
    const float nm = fmaxf(m, p.x);
    s = s * __expf(m - nm) + p.y * __expf(p.x - nm);
    m = nm;
  }
  ws[OFF_V + (size_t)b*NLQ + j] = __expf(-m) / s;
}

// ===== M (MFMA): M[d,j] = v(j) * sum_k (C[d,k]*u(k)) * S_[k,j], K-step 64 ===
__global__ __launch_bounds__(256) void k_m(const float* __restrict__ C,
                                           float* __restrict__ ws) {
  __shared__ ushort Cp[32][72];
  __shared__ ushort Ts[128][72];
  __shared__ float u_l[1024];
  __shared__ float v_l[128];
  const int n  = blockIdx.x;
  const int rr = n & 7, qq = n >> 3;
  const int dq = qq & 7;                // member: d-tile (32 rows)
  const int b  = (qq >> 3) * 8 + rr;    // group: batch (same XCD)
  const int t  = threadIdx.x;
  const int l  = t & 63, w = t >> 6;
  const int wd = w & 1, wj = w >> 1;
  const int lm = l & 15, lg = l >> 4;
  for (int kk = t; kk < 1024; kk += 256) u_l[kk] = ws[OFF_U + (size_t)b*NLC + kk];
  if (t < 128) v_l[t] = ws[OFF_V + (size_t)b*NLQ + t];

  f32x4 acc[4];
  #pragma unroll
  for (int nf = 0; nf < 4; ++nf) acc[nf] = (f32x4)0.0f;

  const float*  Cb   = C + (size_t)b*ND*NLC + (size_t)dq*32*NLC;
  const ushort* SBTg = (const ushort*)(ws + OFF_SBT) + (size_t)b*NLQ*NLC;

  for (int kt = 0; kt < 16; ++kt) {
    const int k0 = kt*64;
    __syncthreads();
    {                                    // stage C' = C*u (32 d x 64 k)
      const int dl = t >> 3, kq = t & 7;
      const float4 c0 = *(const float4*)&Cb[(size_t)dl*NLC + k0 + kq*8];
      const float4 c1 = *(const float4*)&Cb[(size_t)dl*NLC + k0 + kq*8 + 4];
      const int kb = k0 + kq*8;
      uint4 pk;
      pk.x = cvtpk(c0.x * u_l[kb+0], c0.y * u_l[kb+1]);
      pk.y = cvtpk(c0.z * u_l[kb+2], c0.w * u_l[kb+3]);
      pk.z = cvtpk(c1.x * u_l[kb+4], c1.y * u_l[kb+5]);
      pk.w = cvtpk(c1.z * u_l[kb+6], c1.w * u_l[kb+7]);
      *(uint4*)&Cp[dl][kq*8] = pk;
    }
    #pragma unroll
    for (int p = 0; p < 4; ++p) {        // stage S_^T tile (128 j x 64 k)
      const int f = p*256 + t;
      const int jr = f >> 3, k8 = (f & 7)*8;
      *(uint4*)&Ts[jr][k8] = *(const uint4*)&SBTg[(size_t)jr*NLC + k0 + k8];
    }
    __syncthreads();
    #pragma unroll
    for (int ks = 0; ks < 2; ++ks) {
      union { uint32_t u[4]; bf16x8 v; } ca;
      *(uint4*)ca.u = *(const uint4*)&Cp[wd*16 + lm][ks*32 + lg*8];
      #pragma unroll
      for (int nf = 0; nf < 4; ++nf) {
        union { uint32_t u[4]; bf16x8 v; } cb;
        *(uint4*)cb.u = *(const uint4*)&Ts[wj*64 + nf*16 + lm][ks*32 + lg*8];
        acc[nf] = __builtin_amdgcn_mfma_f32_16x16x32_bf16(ca.v, cb.v, acc[nf], 0, 0, 0);
      }
    }
  }
  ushort* Mp = (ushort*)(ws + OFF_M) + (size_t)b*ND*NLQ + (size_t)dq*32*NLQ;
  #pragma unroll
  for (int nf = 0; nf < 4; ++nf) {
    const int j = wj*64 + nf*16 + lm;
    const float vj = v_l[j];
    #pragma unroll
    for (int r = 0; r < 4; ++r) {
      const int d = wd*16 + lg*4 + r;
      Mp[(size_t)d*NLQ + j] = (ushort)f2bf(acc[nf][r] * vj);
    }
  }
}

// ==== final (MFMA, swapped operands A=S_, B=Q/M from swizzled LDS) ==========
// D[m=i][n=d]: thread holds 4 consecutive i at fixed d -> direct full-line
// stores. s-loop FULLY unrolled (compile-time selects); threefry rotates via
// rotateleft builtin (v_alignbit, 1 op vs 3).
__global__ __launch_bounds__(256, 4) void k_final(const float* __restrict__ C,
                                                  float* __restrict__ ws,
                                                  float* __restrict__ out) {
  __shared__ __align__(16) ushort St[128][128];   // [i][j] bf16, swizzled 32KB
  __shared__ __align__(16) ushort Qt[16][128];    // [d][j] bf16, swizzled  4KB
  __shared__ __align__(16) ushort Mt[16][128];    // [d][j] bf16, swizzled  4KB

  const int n  = blockIdx.x;
  const int r8 = n & 7, q = n >> 3;       // q in 0..1023
  const int m  = q & 15;                  // member: d0 block (16 rows)
  const int g  = (q >> 4) * 8 + r8;       // group 0..511 = (i0, b), one XCD
  const int b  = g & 63;
  const int i0 = (g >> 6) * 128;
  const int d0 = m * 16;
  const int t  = threadIdx.x;

  const ushort* Sp = (const ushort*)(ws + OFF_SBF) + ((size_t)b*NLC + i0)*NLQ;
  #pragma unroll
  for (int p = 0; p < 8; ++p) {           // S_ bf16: swizzled uint4 copies
    const int f  = p*256 + t;
    const int jo = f & 15;
    const int il = f >> 4;
    *(uint4*)&St[il][(jo*8) ^ ((il & 7) << 3)] =
        *(const uint4*)&Sp[(size_t)il*NLQ + jo*8];
  }
  const ushort* Qp = (const ushort*)(ws + OFF_QB) + (size_t)b*ND*NLQ + (size_t)d0*NLQ;
  const ushort* Mp = (const ushort*)(ws + OFF_M)  + (size_t)b*ND*NLQ + (size_t)d0*NLQ;
  {                                       // Q/M bf16: swizzled uint4 copies
    const int jo = t & 15;
    const int dl = t >> 4;
    const int col = (jo*8) ^ ((dl & 7) << 3);
    *(uint4*)&Qt[dl][col] = *(const uint4*)&Qp[(size_t)dl*NLQ + jo*8];
    *(uint4*)&Mt[dl][col] = *(const uint4*)&Mp[(size_t)dl*NLQ + jo*8];
  }
  __syncthreads();

  const int w  = t >> 6;
  const int l  = t & 63;
  const int lm = l & 15;
  const int lg = l >> 4;
  const int sw = (lm & 7) << 3;

  f32x4 accA[2], accB[2];
  #pragma unroll
  for (int f = 0; f < 2; ++f) { accA[f] = (f32x4)0.0f; accB[f] = (f32x4)0.0f; }

  #pragma unroll
  for (int ks = 0; ks < 4; ++ks) {
    const int koff = (ks*32 + lg*8) ^ sw;
    const bf16x8 qfk = *(const bf16x8*)&Qt[lm][koff];  // B-frag: row d0+lm
    const bf16x8 mfk = *(const bf16x8*)&Mt[lm][koff];
    #pragma unroll
    for (int f = 0; f < 2; ++f) {
      const bf16x8 sf = *(const bf16x8*)&St[(w*2 + f)*16 + lm][koff];
      accA[f] = __builtin_amdgcn_mfma_f32_16x16x32_bf16(sf, qfk, accA[f], 0, 0, 0);
      accB[f] = __builtin_amdgcn_mfma_f32_16x16x32_bf16(sf, mfk, accB[f], 0, 0, 0);
    }
  }

  // epilogue: thread owns d = d0+lm, i = i0 + w*32 + f*16 + lg*4 (+r 0..3).
  // Per d-row the wave covers one aligned 128B line via the adjacent f=0/f=1
  // store pair -> no partial-line RMW window. FULL unroll: s compile-time.
  const int d  = d0 + lm;
  const int ib = i0 + w*32 + lg*4;
  const float* Crow = C + ((size_t)b*ND + d)*NLC;
  const float4 c0 = *(const float4*)&Crow[ib];
  const float4 c1 = *(const float4*)&Crow[ib + 16];
  const float cv0[4] = {c0.x, c0.y, c0.z, c0.w};
  const float cv1[4] = {c1.x, c1.y, c1.z, c1.w};
  #pragma unroll
  for (int s = 0; s < 4; ++s) {
    const uint32_t nb0 = ((((uint32_t)b << 10) + (uint32_t)(s*ND + d)) << 10)
                         + (uint32_t)ib;
    float o0[4], o1[4];
    #pragma unroll
    for (int e = 0; e < 4; ++e) {
      const uint32_t bits0 = threefry_xor(0u, nb0 + (uint32_t)e);
      const uint32_t bits1 = threefry_xor(0u, nb0 + 16u + (uint32_t)e);
      float va, vb;
      if (s == 0)      { va = cv0[e];             vb = cv1[e]; }
      else if (s == 1) { va = accA[0][e];         vb = accA[1][e]; }
      else if (s == 2) { va = cv0[e]*accA[0][e];  vb = cv1[e]*accA[1][e]; }
      else             { va = cv0[e]*accB[0][e];  vb = cv1[e]*accB[1][e]; }
      // u < 0.9f  <=>  bits>>9 < 7549747  <=>  bits < 7549747*512
      o0[e] = (bits0 < 3865470464u) ? va * INVKEEP : 0.0f;
      o1[e] = (bits1 < 3865470464u) ? vb * INVKEEP : 0.0f;
    }
    *(float4*)&out[nb0]      = make_float4(o0[0], o0[1], o0[2], o0[3]);
    *(float4*)&out[nb0 + 16] = make_float4(o1[0], o1[1], o1[2], o1[3]);
  }
}

extern "C" void kernel_launch(void* const* d_in, const int* in_sizes, int n_in,
                              void* d_out, int out_size, void* d_ws, size_t ws_size,
                              hipStream_t stream) {
  (void)in_sizes; (void)n_in; (void)out_size; (void)ws_size;
  const float* C = (const float*)d_in[0];
  const float* Q = (const float*)d_in[1];
  const float* W = (const float*)d_in[2];
  float* out = (float*)d_out;
  float* ws  = (float*)d_ws;

  hipLaunchKernelGGL(k_prep,  dim3(256),  dim3(256), 0, stream, Q, W, ws);
  hipLaunchKernelGGL(k_s,     dim3(512),  dim3(256), 0, stream, C, ws);
  hipLaunchKernelGGL(k_cred,  dim3(NB),   dim3(128), 0, stream, ws);
  hipLaunchKernelGGL(k_m,     dim3(512),  dim3(256), 0, stream, C, ws);
  hipLaunchKernelGGL(k_final, dim3(8192), dim3(256), 0, stream, C, ws, out);
}